// Round 6
// baseline (191.742 us; speedup 1.0000x reference)
//
#include <hip/hip_runtime.h>

// YOLOv1-style loss: S=7, B=2, C=20, L=49, n=16384.
// preds row: [ pcls: 980 | pconf: 98 | pbox: 392 ] = 1470 floats
// labels row: L * [ obj(1) | tcls(20) | tbox(4) ] = 1225 floats
// Weights: NOOBJ=0.5, OBJ=0.5, CLS=0.5, COORD=2.5
//
// R13: persistent pipelined waves. Evidence: R9/R10 (179MB logical) =
// 65us = 2.75 TB/s; R8/R12 (116MB gated) = ~56.5us = 2.05 TB/s. Reads
// are capped by per-CU outstanding-line capacity (~64 lines x 64B /
// ~900cy => ~2.8 TB/s); one-shot waves run 27% BELOW the cap because
// drain/exit/launch windows empty the miss queues (m13 copy kernel:
// 6.3 TB/s reads via grid-stride waves that always have next loads in
// flight). Fix: each wave processes 8 consecutive samples (512 blocks,
// 2/CU, all resident) with a 2-deep pipeline -- sample g's gated
// gathers overlap sample g+1's stream (objf+conf+labels->LDS dbuf);
// objf(g+1) lands one iteration before it gates g+1's gathers, so the
// serial objf->gather chain exists only at g=0. Full unroll => static
// LDS offsets/parity (no scratch, rule #20). Queues never drain ->
// cap-rate on gated traffic: predict ~43-47us kernel, total ~174.

#define L_CELLS 49
#define PRED_ROW 1470
#define LAB_ROW 1225
#define CONF_BASE 980
#define BOX_BASE 1078
#define W_NOOBJ 0.5f
#define W_OBJ 0.5f
#define W_CLS 0.5f
#define W_COORD 2.5f
#define INV_S (1.0f / 7.0f)

#define LAB_SLOTS 308  // ceil((3 + 1225)/4); 16B tail overread page-safe
#define WAVE_SLOTS 310 // +pad
#define K_SAMP 8       // samples per wave

typedef int __attribute__((address_space(1))) as1_int;
typedef int __attribute__((address_space(3))) as3_int;

__global__ __launch_bounds__(256, 2) void yolo_loss_kernel(
    const float* __restrict__ preds, const float* __restrict__ labels,
    float* __restrict__ ws) {
  // double-buffered labels stage per wave: 4 waves x 2 x 310 x 16B = 39,680B
  __shared__ float4 st[4][2][WAVE_SLOTS];

  const int tid = threadIdx.x;
  const int w = tid >> 6;
  const int lane = tid & 63;
  const int wid = blockIdx.x * 4 + w;
  const bool act = lane < L_CELLS;
  // clamped lane for unconditional objf gather (lanes 49-63 re-read
  // lane 48's line -- in-bounds, L1 hit, avoids a value-select that
  // would force an early vmcnt wait)
  const int ll = (lane < L_CELLS) ? lane : (L_CELLS - 1);

  float objf_v[2];
  float2 cf_v[2];

  // ---- prologue: issue stream(0) into buf 0 ----
  {
    const int s = wid * K_SAMP;
    const float* lrow = labels + (size_t)s * LAB_ROW;
    const float* rp = preds + (size_t)s * PRED_ROW;
    objf_v[0] = lrow[25 * ll];
    cf_v[0] = *(const float2*)(rp + CONF_BASE + 2 * lane);  // <1470, in-row
    float* dst = (float*)st[w][0];
    size_t ga = ((size_t)s * LAB_ROW) & ~(size_t)3;
#pragma unroll
    for (int r = 0; r < 5; ++r) {
      int i = lane + 64 * r;
      if (i < LAB_SLOTS)
        __builtin_amdgcn_global_load_lds(
            (const as1_int*)(labels + ga + 4 * (size_t)i),
            (as3_int*)(dst + 256 * r), 16, 0, 0);
    }
  }

  float acc = 0.0f;

#pragma unroll
  for (int g = 0; g < K_SAMP; ++g) {
    const int cur = g & 1;
    const int s = wid * K_SAMP + g;
    const float* rp = preds + (size_t)s * PRED_ROW;

    // objf(g) was drained by the previous iteration's vmcnt(0)
    // (g=0: compiler inserts a counted wait -- prologue transient only)
    const bool objm = act && (objf_v[cur] != 0.0f);

    // gated gathers for current sample
    float2 pc[10];
    float2 bq[4];
    if (objm) {
#pragma unroll
      for (int k = 0; k < 10; ++k)
        pc[k] = *(const float2*)(rp + 20 * lane + 2 * k);  // 8B-aligned
#pragma unroll
      for (int k = 0; k < 4; ++k)
        bq[k] = *(const float2*)(rp + BOX_BASE + 8 * lane + 2 * k);
    }

    // issue stream(g+1): overlaps the gather wait; its one-iteration
    // head start is what keeps the miss queues full.
    if (g + 1 < K_SAMP) {
      const int nxt = cur ^ 1;
      const int sn = s + 1;
      const float* lrown = labels + (size_t)sn * LAB_ROW;
      const float* rpn = preds + (size_t)sn * PRED_ROW;
      objf_v[nxt] = lrown[25 * ll];
      cf_v[nxt] = *(const float2*)(rpn + CONF_BASE + 2 * lane);
      float* dst = (float*)st[w][nxt];
      size_t ga = ((size_t)sn * LAB_ROW) & ~(size_t)3;
#pragma unroll
      for (int r = 0; r < 5; ++r) {
        int i = lane + 64 * r;
        if (i < LAB_SLOTS)
          __builtin_amdgcn_global_load_lds(
              (const as1_int*)(labels + ga + 4 * (size_t)i),
              (as3_int*)(dst + 256 * r), 16, 0, 0);
      }
    }

    // drain before consuming LDS + gathered regs (stream(g+1) drains
    // too -- it completes ~same time as the gathers; harmless)
    asm volatile("s_waitcnt vmcnt(0)" ::: "memory");
    __builtin_amdgcn_sched_barrier(0);

    // loff = (s*1225) & 3 = s & 3 = g & 3 (wid*8 = 0 mod 4)
    const float* lab = (const float*)st[w][cur] + (g & 3);  // lab[25l+k]

    if (act) {
      const int l = lane;
      float c0v = cf_v[cur].x, c1v = cf_v[cur].y;
      if (objm) {
        float bx[8] = {bq[0].x, bq[0].y, bq[1].x, bq[1].y,
                       bq[2].x, bq[2].y, bq[3].x, bq[3].y};
        float tx = lab[25 * l + 21], ty = lab[25 * l + 22];
        float tw = lab[25 * l + 23], th = lab[25 * l + 24];
        float t0 = tx * INV_S, t1 = ty * INV_S, t2 = tw, t3 = th;

        float iou[2], rmse2[2];
#pragma unroll
        for (int b = 0; b < 2; ++b) {
          float o0 = bx[4 * b + 0] * INV_S;
          float o1 = bx[4 * b + 1] * INV_S;
          float o2 = bx[4 * b + 2] * bx[4 * b + 2];
          float o3 = bx[4 * b + 3] * bx[4 * b + 3];
          float left = fmaxf(t0 - 0.5f * t2, o0 - 0.5f * o2);
          float right = fminf(t0 + 0.5f * t2, o0 + 0.5f * o2);
          float top = fmaxf(t1 - 0.5f * t3, o1 - 0.5f * o3);
          float bot = fminf(t1 + 0.5f * t3, o1 + 0.5f * o3);
          float wd = right - left;
          float h = bot - top;
          bool invalid = (wd < 0.0f) || (h < 0.0f);
          float inter = invalid ? 0.0f : wd * h;
          float uni = t2 * t3 + o2 * o3 - inter;
          iou[b] = invalid ? 0.0f : inter / fmaxf(uni, 1e-12f);
          float d0 = t0 - o0, d1 = t1 - o1, d2 = t2 - o2, d3 = t3 - o3;
          rmse2[b] = d0 * d0 + d1 * d1 + d2 * d2 + d3 * d3;  // sqrt monotone
        }

        float max_iou = fmaxf(iou[0], iou[1]);
        // jnp.argmax/argmin: first index wins ties -> strict cmp for idx 1
        int best;
        if (max_iou > 0.0f)
          best = (iou[1] > iou[0]) ? 1 : 0;
        else
          best = (rmse2[1] < rmse2[0]) ? 1 : 0;
        float best_iou = iou[best];

        float cb = (best == 0) ? c0v : c1v;
        float co = (best == 0) ? c1v : c0v;
        float db = best_iou - cb;
        float obj_term = W_OBJ * db * db + W_NOOBJ * co * co;

        // cls: pcls from gathered regs, tcls from staged labels
        float clsacc = 0.0f;
#pragma unroll
        for (int k = 0; k < 10; ++k) {
          float d0 = lab[25 * l + 1 + 2 * k] - pc[k].x;
          float d1 = lab[25 * l + 2 + 2 * k] - pc[k].y;
          clsacc += d0 * d0 + d1 * d1;
        }
        obj_term += W_CLS * clsacc;

        // coord: (tx, ty, sqrt(tw), sqrt(th)) vs best raw box
        float e0 = tx - bx[best * 4 + 0];
        float e1 = ty - bx[best * 4 + 1];
        float e2 = sqrtf(tw) - bx[best * 4 + 2];
        float e3 = sqrtf(th) - bx[best * 4 + 3];
        obj_term += W_COORD * (e0 * e0 + e1 * e1 + e2 * e2 + e3 * e3);

        acc += obj_term;
      } else {
        acc += W_NOOBJ * (c0v * c0v + c1v * c1v);
      }
    }
  }

  // ---- reduce: wave(64) shuffle -> one ws slot per wave ----
#pragma unroll
  for (int o = 32; o > 0; o >>= 1) acc += __shfl_down(acc, o);
  if (lane == 0) ws[wid] = acc;
}

__global__ __launch_bounds__(1024) void final_reduce_kernel(
    const float* __restrict__ ws, float* __restrict__ out, int m) {
  float acc = 0.0f;
  for (int i = threadIdx.x; i < m; i += 1024) acc += ws[i];
#pragma unroll
  for (int o = 32; o > 0; o >>= 1) acc += __shfl_down(acc, o);
  __shared__ float wsum[16];
  int wave = threadIdx.x >> 6;
  int lane = threadIdx.x & 63;
  if (lane == 0) wsum[wave] = acc;
  __syncthreads();
  if (threadIdx.x == 0) {
    float sum = 0.0f;
#pragma unroll
    for (int i = 0; i < 16; ++i) sum += wsum[i];
    out[0] = sum;
  }
}

extern "C" void kernel_launch(void* const* d_in, const int* in_sizes, int n_in,
                              void* d_out, int out_size, void* d_ws, size_t ws_size,
                              hipStream_t stream) {
  const float* preds = (const float*)d_in[0];
  const float* labels = (const float*)d_in[1];
  float* out = (float*)d_out;
  float* ws = (float*)d_ws;
  int n = in_sizes[0] / PRED_ROW;        // 16384
  int blocks = n / (4 * K_SAMP);         // 512 (4 waves/block, 8 samples/wave)
  int nwaves = blocks * 4;               // 2048 partial sums

  yolo_loss_kernel<<<blocks, 256, 0, stream>>>(preds, labels, ws);
  final_reduce_kernel<<<1, 1024, 0, stream>>>(ws, out, nwaves);
}

// Round 7
// 191.203 us; speedup vs baseline: 1.0028x; 1.0028x over previous
//
#include <hip/hip_runtime.h>

// YOLOv1-style loss: S=7, B=2, C=20, L=49, n=16384.
// preds row: [ pcls: 980 | pconf: 98 | pbox: 392 ] = 1470 floats
// labels row: L * [ obj(1) | tcls(20) | tbox(4) ] = 1225 floats
// Weights: NOOBJ=0.5, OBJ=0.5, CLS=0.5, COORD=2.5
//
// R14: TRUE counted-vmcnt pipeline. R13 post-mortem: its vmcnt(0)
// drained the just-issued prefetch -> zero overlap (fake pipeline) +
// 8 waves/CU -> kernel back to ~64us. Fix: per iteration, pinned
// regions [gathers(g)] [P(g+1): objf,conf,5xlds = exactly 7 instrs]
// then s_waitcnt vmcnt(7): leaves exactly P(g+1) in flight; P(g) LDS
// writes + gathers(g) complete (in-order vmcnt, m135). objf(g+1) is
// oldest of the 7 -> compiler's own counted wait before next objm
// branch ~ vmcnt(6), near-zero stall. Every wave keeps >=7 loads
// outstanding through compute/reduce -> per-CU miss tracker (the
// ~2.75 TB/s line-rate cap, R12 fit) never drains. K_SAMP=4, 1024
// blocks = 4 blk/CU resident, 16 waves/CU, LDS 39,680B, VGPR<=128.
// Predict kernel ~40-46us, total ~172-178.

#define L_CELLS 49
#define PRED_ROW 1470
#define LAB_ROW 1225
#define CONF_BASE 980
#define BOX_BASE 1078
#define W_NOOBJ 0.5f
#define W_OBJ 0.5f
#define W_CLS 0.5f
#define W_COORD 2.5f
#define INV_S (1.0f / 7.0f)

#define LAB_SLOTS 308  // ceil((3 + 1225)/4); 16B tail overread page-safe
#define WAVE_SLOTS 310 // +pad
#define K_SAMP 4       // samples per wave; 1024 blocks -> all resident

typedef int __attribute__((address_space(1))) as1_int;
typedef int __attribute__((address_space(3))) as3_int;

__global__ __launch_bounds__(256, 4) void yolo_loss_kernel(
    const float* __restrict__ preds, const float* __restrict__ labels,
    float* __restrict__ ws) {
  // double-buffered labels stage per wave: 4 x 2 x 310 x 16B = 39,680B
  __shared__ float4 st[4][2][WAVE_SLOTS];

  const int tid = threadIdx.x;
  const int w = tid >> 6;
  const int lane = tid & 63;
  const int wid = blockIdx.x * 4 + w;
  const bool act = lane < L_CELLS;
  // clamped lane: lanes 49-63 re-read lane 48's line (in-bounds, merges
  // in MSHR with the labels stage touching the same line)
  const int ll = act ? lane : (L_CELLS - 1);

  float objf_v[2];
  float2 cf_v[2];

  // ---- prologue: issue P(0) into buf 0; objf FIRST (oldest -> minimal
  // counted wait at its use) ----
  {
    const int s0 = wid * K_SAMP;
    objf_v[0] = labels[(size_t)s0 * LAB_ROW + 25 * ll];
    __builtin_amdgcn_sched_barrier(0);
    const float* rp0 = preds + (size_t)s0 * PRED_ROW;
    cf_v[0] = *(const float2*)(rp0 + CONF_BASE + 2 * lane);  // in-row
    float* dst = (float*)st[w][0];
    size_t ga = ((size_t)s0 * LAB_ROW) & ~(size_t)3;
#pragma unroll
    for (int r = 0; r < 5; ++r) {
      int i = lane + 64 * r;
      if (i < LAB_SLOTS)
        __builtin_amdgcn_global_load_lds(
            (const as1_int*)(labels + ga + 4 * (size_t)i),
            (as3_int*)(dst + 256 * r), 16, 0, 0);
    }
    __builtin_amdgcn_sched_barrier(0);
  }

  float acc = 0.0f;

#pragma unroll
  for (int g = 0; g < K_SAMP; ++g) {
    const int cur = g & 1;
    const int s = wid * K_SAMP + g;
    const float* rp = preds + (size_t)s * PRED_ROW;

    // compiler inserts its own counted vmcnt here for objf_v[cur]
    // (oldest of the 7 outstanding P(g) loads -> ~vmcnt(6))
    const bool objm = act && (objf_v[cur] != 0.0f);

    // ---- region A: gated gathers for sample g ----
    float2 pc[10];
    float2 bq[4];
    if (objm) {
#pragma unroll
      for (int k = 0; k < 10; ++k)
        pc[k] = *(const float2*)(rp + 20 * lane + 2 * k);  // 16B-aligned run
#pragma unroll
      for (int k = 0; k < 4; ++k)
        bq[k] = *(const float2*)(rp + BOX_BASE + 8 * lane + 2 * k);
    }
    __builtin_amdgcn_sched_barrier(0);

    // ---- region B: P(g+1), EXACTLY 7 instrs (1 dword + 1 dwordx2 +
    // 5 global_load_lds), objf first ----
    if (g + 1 < K_SAMP) {
      const int nxt = cur ^ 1;
      const int sn = s + 1;
      objf_v[nxt] = labels[(size_t)sn * LAB_ROW + 25 * ll];
      __builtin_amdgcn_sched_barrier(0);
      const float* rpn = preds + (size_t)sn * PRED_ROW;
      cf_v[nxt] = *(const float2*)(rpn + CONF_BASE + 2 * lane);
      float* dst = (float*)st[w][nxt];
      size_t ga = ((size_t)sn * LAB_ROW) & ~(size_t)3;
#pragma unroll
      for (int r = 0; r < 5; ++r) {
        int i = lane + 64 * r;
        if (i < LAB_SLOTS)
          __builtin_amdgcn_global_load_lds(
              (const as1_int*)(labels + ga + 4 * (size_t)i),
              (as3_int*)(dst + 256 * r), 16, 0, 0);
      }
    }
    __builtin_amdgcn_sched_barrier(0);

    // ---- counted wait: leave exactly P(g+1) in flight; all of P(g)'s
    // LDS writes and gathers(g) are complete ----
    if (g + 1 < K_SAMP)
      asm volatile("s_waitcnt vmcnt(7)" ::: "memory");
    else
      asm volatile("s_waitcnt vmcnt(0)" ::: "memory");
    __builtin_amdgcn_sched_barrier(0);

    // loff = (s*1225)&3 = s&3 = g (wid*K_SAMP ≡ 0 mod 4)
    const float* lab = (const float*)st[w][cur] + g;  // lab[25l + k]

    if (act) {
      const int l = lane;
      float c0v = cf_v[cur].x, c1v = cf_v[cur].y;
      if (objm) {
        float bx[8] = {bq[0].x, bq[0].y, bq[1].x, bq[1].y,
                       bq[2].x, bq[2].y, bq[3].x, bq[3].y};
        float tx = lab[25 * l + 21], ty = lab[25 * l + 22];
        float tw = lab[25 * l + 23], th = lab[25 * l + 24];
        float t0 = tx * INV_S, t1 = ty * INV_S, t2 = tw, t3 = th;

        float iou[2], rmse2[2];
#pragma unroll
        for (int b = 0; b < 2; ++b) {
          float o0 = bx[4 * b + 0] * INV_S;
          float o1 = bx[4 * b + 1] * INV_S;
          float o2 = bx[4 * b + 2] * bx[4 * b + 2];
          float o3 = bx[4 * b + 3] * bx[4 * b + 3];
          float left = fmaxf(t0 - 0.5f * t2, o0 - 0.5f * o2);
          float right = fminf(t0 + 0.5f * t2, o0 + 0.5f * o2);
          float top = fmaxf(t1 - 0.5f * t3, o1 - 0.5f * o3);
          float bot = fminf(t1 + 0.5f * t3, o1 + 0.5f * o3);
          float wd = right - left;
          float h = bot - top;
          bool invalid = (wd < 0.0f) || (h < 0.0f);
          float inter = invalid ? 0.0f : wd * h;
          float uni = t2 * t3 + o2 * o3 - inter;
          iou[b] = invalid ? 0.0f : inter / fmaxf(uni, 1e-12f);
          float d0 = t0 - o0, d1 = t1 - o1, d2 = t2 - o2, d3 = t3 - o3;
          rmse2[b] = d0 * d0 + d1 * d1 + d2 * d2 + d3 * d3;  // sqrt monotone
        }

        float max_iou = fmaxf(iou[0], iou[1]);
        // jnp.argmax/argmin: first index wins ties -> strict cmp for idx 1
        int best;
        if (max_iou > 0.0f)
          best = (iou[1] > iou[0]) ? 1 : 0;
        else
          best = (rmse2[1] < rmse2[0]) ? 1 : 0;
        float best_iou = iou[best];

        float cb = (best == 0) ? c0v : c1v;
        float co = (best == 0) ? c1v : c0v;
        float db = best_iou - cb;
        float obj_term = W_OBJ * db * db + W_NOOBJ * co * co;

        // cls: pcls from gathered regs, tcls from staged labels
        float clsacc = 0.0f;
#pragma unroll
        for (int k = 0; k < 10; ++k) {
          float d0 = lab[25 * l + 1 + 2 * k] - pc[k].x;
          float d1 = lab[25 * l + 2 + 2 * k] - pc[k].y;
          clsacc += d0 * d0 + d1 * d1;
        }
        obj_term += W_CLS * clsacc;

        // coord: (tx, ty, sqrt(tw), sqrt(th)) vs best raw box
        float e0 = tx - bx[best * 4 + 0];
        float e1 = ty - bx[best * 4 + 1];
        float e2 = sqrtf(tw) - bx[best * 4 + 2];
        float e3 = sqrtf(th) - bx[best * 4 + 3];
        obj_term += W_COORD * (e0 * e0 + e1 * e1 + e2 * e2 + e3 * e3);

        acc += obj_term;
      } else {
        acc += W_NOOBJ * (c0v * c0v + c1v * c1v);
      }
    }
  }

  // ---- reduce: wave(64) shuffle -> one ws slot per wave ----
#pragma unroll
  for (int o = 32; o > 0; o >>= 1) acc += __shfl_down(acc, o);
  if (lane == 0) ws[wid] = acc;
}

__global__ __launch_bounds__(1024) void final_reduce_kernel(
    const float* __restrict__ ws, float* __restrict__ out, int m) {
  float acc = 0.0f;
  for (int i = threadIdx.x; i < m; i += 1024) acc += ws[i];
#pragma unroll
  for (int o = 32; o > 0; o >>= 1) acc += __shfl_down(acc, o);
  __shared__ float wsum[16];
  int wave = threadIdx.x >> 6;
  int lane = threadIdx.x & 63;
  if (lane == 0) wsum[wave] = acc;
  __syncthreads();
  if (threadIdx.x == 0) {
    float sum = 0.0f;
#pragma unroll
    for (int i = 0; i < 16; ++i) sum += wsum[i];
    out[0] = sum;
  }
}

extern "C" void kernel_launch(void* const* d_in, const int* in_sizes, int n_in,
                              void* d_out, int out_size, void* d_ws, size_t ws_size,
                              hipStream_t stream) {
  const float* preds = (const float*)d_in[0];
  const float* labels = (const float*)d_in[1];
  float* out = (float*)d_out;
  float* ws = (float*)d_ws;
  int n = in_sizes[0] / PRED_ROW;  // 16384
  int blocks = n / (4 * K_SAMP);   // 1024 (4 waves/block, 4 samples/wave)
  int nwaves = blocks * 4;         // 4096 partial sums

  yolo_loss_kernel<<<blocks, 256, 0, stream>>>(preds, labels, ws);
  final_reduce_kernel<<<1, 1024, 0, stream>>>(ws, out, nwaves);
}

// Round 8
// 185.662 us; speedup vs baseline: 1.0327x; 1.0298x over previous
//
#include <hip/hip_runtime.h>

// YOLOv1-style loss: S=7, B=2, C=20, L=49, n=16384.
// preds row: [ pcls: 980 | pconf: 98 | pbox: 392 ] = 1470 floats
// labels row: L * [ obj(1) | tcls(20) | tbox(4) ] = 1225 floats
// Weights: NOOBJ=0.5, OBJ=0.5, CLS=0.5, COORD=2.5
//
// R15 = restore R8, the empirical optimum (185.0us total, best of 8
// measured rounds). Session evidence (R8-R14): demand-read service rate
// for this op's pattern pins at ~2.0-2.8 TB/s INDEPENDENT of occupancy
// (9-57%, R10 vs R9), access shape (stream vs gather, R10 vs R9),
// in-flight depth (counted vmcnt(7) pipeline R14 regressed to ~63us),
// and traffic (179->116MB gave only -12% time). Gated two-phase one-shot
// (R8=185.0, R12=186.2) is the converged structure; all pipeline /
// persistent-wave redesigns (R9,R10,R13,R14: 190-193) lost. Total =
// ~114us harness re-poison fills (385MB @ 6.8TB/s = 85% peak, fixed) +
// ~14us launch/reduce + ~57us this kernel (vs 42us traffic floor at the
// measured rate cap -- the residue is the cap, not schedulable).

#define L_CELLS 49
#define PRED_ROW 1470
#define LAB_ROW 1225
#define CONF_BASE 980
#define BOX_BASE 1078
#define W_NOOBJ 0.5f
#define W_OBJ 0.5f
#define W_CLS 0.5f
#define W_COORD 2.5f
#define INV_S (1.0f / 7.0f)

#define LAB_SLOTS 308  // ceil((3 + 1225)/4)
#define WAVE_SLOTS 310 // +pad

__global__ __launch_bounds__(256, 6) void yolo_loss_kernel(
    const float* __restrict__ preds, const float* __restrict__ labels,
    float* __restrict__ ws) {
  __shared__ float4 st[4][WAVE_SLOTS];  // 19840 B/block

  const int tid = threadIdx.x;
  const int w = tid >> 6;
  const int lane = tid & 63;
  const int s = blockIdx.x * 4 + w;
  float4* stw = st[w];

  // ---- stage labels row only (align-down; <=16B page-safe overread on
  // final row -- verified passing R5-R14) ----
  size_t g0 = (size_t)s * LAB_ROW;
  size_t ga = g0 & ~(size_t)3;
  int loff = (int)(g0 - ga);
#pragma unroll
  for (int r = 0; r < 5; ++r) {
    int i = lane + 64 * r;
    if (i < LAB_SLOTS) stw[i] = *(const float4*)(labels + ga + 4 * (size_t)i);
  }

  const float* lab = (const float*)stw + loff;  // lab[25l + k]
  const float* rp = preds + (size_t)s * PRED_ROW;

  float acc = 0.0f;
  if (lane < L_CELLS) {
    const int l = lane;
    // conf: coalesced direct load, 8B/lane, 8B-aligned
    float2 cf = *(const float2*)(rp + CONF_BASE + 2 * l);
    float c0v = cf.x, c1v = cf.y;
    float objf = lab[25 * l];

    if (objf != 0.0f) {
      // pbox: gated direct, 4x float2 (8B-aligned)
      float bx[8];
#pragma unroll
      for (int k = 0; k < 4; ++k) {
        float2 b2 = *(const float2*)(rp + BOX_BASE + 8 * l + 2 * k);
        bx[2 * k] = b2.x;
        bx[2 * k + 1] = b2.y;
      }
      float tx = lab[25 * l + 21], ty = lab[25 * l + 22];
      float tw = lab[25 * l + 23], th = lab[25 * l + 24];
      float t0 = tx * INV_S, t1 = ty * INV_S, t2 = tw, t3 = th;

      float iou[2], rmse2[2];
#pragma unroll
      for (int b = 0; b < 2; ++b) {
        float o0 = bx[4 * b + 0] * INV_S;
        float o1 = bx[4 * b + 1] * INV_S;
        float o2 = bx[4 * b + 2] * bx[4 * b + 2];
        float o3 = bx[4 * b + 3] * bx[4 * b + 3];
        float left = fmaxf(t0 - 0.5f * t2, o0 - 0.5f * o2);
        float right = fminf(t0 + 0.5f * t2, o0 + 0.5f * o2);
        float top = fmaxf(t1 - 0.5f * t3, o1 - 0.5f * o3);
        float bot = fminf(t1 + 0.5f * t3, o1 + 0.5f * o3);
        float wd = right - left;
        float h = bot - top;
        bool invalid = (wd < 0.0f) || (h < 0.0f);
        float inter = invalid ? 0.0f : wd * h;
        float uni = t2 * t3 + o2 * o3 - inter;
        iou[b] = invalid ? 0.0f : inter / fmaxf(uni, 1e-12f);
        float d0 = t0 - o0, d1 = t1 - o1, d2 = t2 - o2, d3 = t3 - o3;
        rmse2[b] = d0 * d0 + d1 * d1 + d2 * d2 + d3 * d3;  // sqrt monotone
      }

      float max_iou = fmaxf(iou[0], iou[1]);
      // jnp.argmax/argmin: first index wins ties -> strict compare for idx 1
      int best;
      if (max_iou > 0.0f)
        best = (iou[1] > iou[0]) ? 1 : 0;
      else
        best = (rmse2[1] < rmse2[0]) ? 1 : 0;
      float best_iou = iou[best];

      float cb = (best == 0) ? c0v : c1v;
      float co = (best == 0) ? c1v : c0v;
      float db = best_iou - cb;
      acc += W_OBJ * db * db + W_NOOBJ * co * co;

      // cls: pcls direct from global (10x float2, 8B-aligned, ~15% lanes),
      // tcls from staged labels
      float clsacc = 0.0f;
#pragma unroll
      for (int k = 0; k < 10; ++k) {
        float2 p = *(const float2*)(rp + 20 * l + 2 * k);
        float d0 = lab[25 * l + 1 + 2 * k] - p.x;
        float d1 = lab[25 * l + 2 + 2 * k] - p.y;
        clsacc += d0 * d0 + d1 * d1;
      }
      acc += W_CLS * clsacc;

      // coord: (tx, ty, sqrt(tw), sqrt(th)) vs best raw box
      float e0 = tx - bx[best * 4 + 0];
      float e1 = ty - bx[best * 4 + 1];
      float e2 = sqrtf(tw) - bx[best * 4 + 2];
      float e3 = sqrtf(th) - bx[best * 4 + 3];
      acc += W_COORD * (e0 * e0 + e1 * e1 + e2 * e2 + e3 * e3);
    } else {
      acc += W_NOOBJ * (c0v * c0v + c1v * c1v);
    }
  }

  // ---- reduce: wave(64) shuffle -> LDS -> one ws slot per block ----
#pragma unroll
  for (int o = 32; o > 0; o >>= 1) acc += __shfl_down(acc, o);

  __shared__ float wsum[4];
  if (lane == 0) wsum[w] = acc;
  __syncthreads();
  if (tid == 0) ws[blockIdx.x] = wsum[0] + wsum[1] + wsum[2] + wsum[3];
}

__global__ __launch_bounds__(1024) void final_reduce_kernel(
    const float* __restrict__ ws, float* __restrict__ out, int m) {
  float acc = 0.0f;
  for (int i = threadIdx.x; i < m; i += 1024) acc += ws[i];
#pragma unroll
  for (int o = 32; o > 0; o >>= 1) acc += __shfl_down(acc, o);
  __shared__ float wsum[16];
  int wave = threadIdx.x >> 6;
  int lane = threadIdx.x & 63;
  if (lane == 0) wsum[wave] = acc;
  __syncthreads();
  if (threadIdx.x == 0) {
    float sum = 0.0f;
#pragma unroll
    for (int i = 0; i < 16; ++i) sum += wsum[i];
    out[0] = sum;
  }
}

extern "C" void kernel_launch(void* const* d_in, const int* in_sizes, int n_in,
                              void* d_out, int out_size, void* d_ws, size_t ws_size,
                              hipStream_t stream) {
  const float* preds = (const float*)d_in[0];
  const float* labels = (const float*)d_in[1];
  float* out = (float*)d_out;
  float* ws = (float*)d_ws;
  int n = in_sizes[0] / PRED_ROW;  // 16384
  int blocks = n / 4;              // 4096 (wave per sample)

  yolo_loss_kernel<<<blocks, 256, 0, stream>>>(preds, labels, ws);
  final_reduce_kernel<<<1, 1024, 0, stream>>>(ws, out, blocks);
}